// Round 1
// baseline (576.428 us; speedup 1.0000x reference)
//
#include <hip/hip_runtime.h>

#define Sdim 4096
#define Ndim 32
#define Hdim 512
#define Mdim (Sdim * Ndim)

#define BM 64
#define BK 32
#define APAD 8

typedef __bf16 bf16x8 __attribute__((ext_vector_type(8)));
typedef float f32x4 __attribute__((ext_vector_type(4)));

__device__ __forceinline__ unsigned short f2bf(float f) {
    union { float f; unsigned u; } x;
    x.f = f;
    unsigned r = x.u + 0x7fffu + ((x.u >> 16) & 1u);  // RNE
    return (unsigned short)(r >> 16);
}

__device__ __forceinline__ void load_lds16(const void* g, void* l) {
    __builtin_amdgcn_global_load_lds(
        (const __attribute__((address_space(1))) void*)g,
        (__attribute__((address_space(3))) void*)l, 16, 0, 0);
}

__device__ __forceinline__ float ftanh(float x) {
    float e = __expf(2.f * x);
    return 1.f - 2.f / (e + 1.f);
}

// ---------------- kernel 0a: bias[n][c] = hidden[n]·W_w[c] + W_b[c] + U_b[c]
__global__ __launch_bounds__(256) void k_prep_bias(
    const float* __restrict__ hidden, const float* __restrict__ Ww,
    const float* __restrict__ Wb, const float* __restrict__ Ubias,
    float* __restrict__ bias) {
    const int idx = blockIdx.x * 256 + threadIdx.x;  // 0..16383
    const int n = idx >> 9, c = idx & 511;
    const float4* hp = (const float4*)(hidden + n * Hdim);
    const float4* wp = (const float4*)(Ww + c * Hdim);
    float s = 0.f;
    for (int i = 0; i < Hdim / 4; ++i) {
        float4 a = hp[i], b = wp[i];
        s += a.x * b.x + a.y * b.y + a.z * b.z + a.w * b.w;
    }
    bias[idx] = s + Wb[c] + Ubias[c];
}

// ---------------- kernel 0b: U_w fp32 -> bf16
__global__ __launch_bounds__(256) void k_cvt(
    const float* __restrict__ src, unsigned short* __restrict__ dst) {
    const int i = blockIdx.x * 256 + threadIdx.x;  // 65536 threads, x4 elems
    float4 v = ((const float4*)src)[i];
    ushort4 u;
    u.x = f2bf(v.x); u.y = f2bf(v.y); u.z = f2bf(v.z); u.w = f2bf(v.w);
    ((ushort4*)dst)[i] = u;
}

// ---------------- kernel 1: fused  score[n][s] = v·tanh(enc@U_wT + bias[n]) (+v_b)
// BM=64 rows x full 512 cols per block, 8 waves (each 64x64), 16x16x32 bf16 MFMA.
__global__ __launch_bounds__(512, 4) void k_gemm_score(
    const float* __restrict__ enc,          // [M, H] fp32
    const unsigned short* __restrict__ Ub,  // [H, H] bf16 (row=out feature, col=k)
    const float* __restrict__ bias,         // [N, H]
    const float* __restrict__ vw,           // [H]
    const float* __restrict__ vbp,          // [1]
    float* __restrict__ score) {            // [N, S]
    __shared__ unsigned short Asm[BM][BK + APAD];  // 80B rows: 2-way banks (free)
    __shared__ unsigned short Bsm[Hdim * BK];      // unpadded, chunk-swizzled
    __shared__ float ssm[BM];

    const int t = threadIdx.x;
    const int lane = t & 63;
    const int w = t >> 6;      // wave 0..7 -> col block w*64
    const int c = lane & 15;
    const int q = lane >> 4;

    const int mBase = blockIdx.x * BM;

    if (t < BM) ssm[t] = 0.f;

    // A staging: thread -> (row, 4-float chunk)
    const int ar = t >> 3;         // 0..63
    const int ac = (t & 7) * 4;    // 0..28
    const float* aptr = enc + (size_t)(mBase + ar) * Hdim + ac;

    // B staging: per wave 4 issues of 16 rows; lane l covers row l>>2,
    // fetches global chunk (l&3)^(row&3)  (XOR swizzle to break bank conflicts)
    const int brow_in = lane >> 2;
    const int bchunk = (lane & 3) ^ (brow_in & 3);

    f32x4 acc[4][4];
#pragma unroll
    for (int i = 0; i < 4; ++i)
#pragma unroll
        for (int j = 0; j < 4; ++j) acc[i][j] = (f32x4){0.f, 0.f, 0.f, 0.f};

    for (int kk = 0; kk < Hdim / BK; ++kk) {
        const int k0 = kk * BK;
        __syncthreads();
        // A: fp32 load -> bf16 cvt -> LDS
        float4 av = *(const float4*)(aptr + k0);
        ushort4 u4;
        u4.x = f2bf(av.x); u4.y = f2bf(av.y); u4.z = f2bf(av.z); u4.w = f2bf(av.w);
        *(ushort4*)&Asm[ar][ac] = u4;
        // B: direct global->LDS DMA, 16B/lane
#pragma unroll
        for (int j = 0; j < 4; ++j) {
            const int row0 = w * 64 + j * 16;
            const unsigned short* g =
                Ub + (size_t)(row0 + brow_in) * Hdim + k0 + bchunk * 8;
            load_lds16(g, &Bsm[row0 * BK]);
        }
        __syncthreads();

        bf16x8 af[4], bfr[4];
#pragma unroll
        for (int mi = 0; mi < 4; ++mi)
            af[mi] = *(const bf16x8*)&Asm[mi * 16 + c][q * 8];
#pragma unroll
        for (int ni = 0; ni < 4; ++ni) {
            const int col = w * 64 + ni * 16 + c;
            const int chunk = q ^ (c & 3);  // un-swizzle
            bfr[ni] = *(const bf16x8*)&Bsm[col * BK + chunk * 8];
        }
#pragma unroll
        for (int mi = 0; mi < 4; ++mi)
#pragma unroll
            for (int ni = 0; ni < 4; ++ni)
                acc[mi][ni] = __builtin_amdgcn_mfma_f32_16x16x32_bf16(
                    af[mi], bfr[ni], acc[mi][ni], 0, 0, 0);
    }

    // epilogue: e = tanh(acc + bias[n][col]);  partial score = sum_col v[col]*e
    float vcol[4];
#pragma unroll
    for (int ni = 0; ni < 4; ++ni) vcol[ni] = vw[w * 64 + ni * 16 + c];

#pragma unroll
    for (int mi = 0; mi < 4; ++mi) {
#pragma unroll
        for (int reg = 0; reg < 4; ++reg) {
            const int r = mi * 16 + q * 4 + reg;  // row in [0,64)
            const int n = r & 31;                 // mBase % 32 == 0
            float p = 0.f;
#pragma unroll
            for (int ni = 0; ni < 4; ++ni) {
                const int col = w * 64 + ni * 16 + c;
                float e = acc[mi][ni][reg] + bias[n * Hdim + col];
                p += vcol[ni] * ftanh(e);
            }
            p += __shfl_xor(p, 1);
            p += __shfl_xor(p, 2);
            p += __shfl_xor(p, 4);
            p += __shfl_xor(p, 8);
            if (c == 0) atomicAdd(&ssm[r], p);
        }
    }
    __syncthreads();
    if (t < BM) {
        const int m = mBase + t;
        score[(m & 31) * Sdim + (m >> 5)] = ssm[t] + vbp[0];
    }
}

// ---------------- kernel 2: softmax over S per n; write [S][N] out + [N][S] ws
__global__ __launch_bounds__(256) void k_softmax(
    const float* __restrict__ score,  // [N][S]
    float* __restrict__ wts,          // ws [N][S]
    float* __restrict__ out_w) {      // d_out+16384, [S][N]
    const int n = blockIdx.x;
    const int t = threadIdx.x;
    const float* sc = score + n * Sdim;
    __shared__ float red[8];

    float mx = -1e30f;
    for (int i = t; i < Sdim; i += 256) mx = fmaxf(mx, sc[i]);
#pragma unroll
    for (int o = 32; o > 0; o >>= 1) mx = fmaxf(mx, __shfl_xor(mx, o));
    if ((t & 63) == 0) red[t >> 6] = mx;
    __syncthreads();
    mx = fmaxf(fmaxf(red[0], red[1]), fmaxf(red[2], red[3]));

    float sum = 0.f;
    for (int i = t; i < Sdim; i += 256) sum += __expf(sc[i] - mx);
#pragma unroll
    for (int o = 32; o > 0; o >>= 1) sum += __shfl_xor(sum, o);
    if ((t & 63) == 0) red[4 + (t >> 6)] = sum;
    __syncthreads();
    sum = red[4] + red[5] + red[6] + red[7];
    const float inv = 1.f / sum;
    for (int i = t; i < Sdim; i += 256) {
        float wv = __expf(sc[i] - mx) * inv;
        wts[n * Sdim + i] = wv;
        out_w[i * Ndim + n] = wv;
    }
}

// ---------------- kernel 3: context[n][h] = sum_s w[n][s] * enc[s][n][h]
__global__ __launch_bounds__(256) void k_context(
    const float* __restrict__ enc, const float* __restrict__ wts,
    float* __restrict__ ctx) {
    const int n = blockIdx.x & 31;
    const int s0 = (blockIdx.x >> 5) * 256;
    const int t = threadIdx.x;
    const int hv = t & 127;  // float4 column
    const int sl = t >> 7;   // 0..1
    float4 a = {0.f, 0.f, 0.f, 0.f};
    for (int i = sl; i < 256; i += 2) {
        const int s = s0 + i;
        const float wv = wts[n * Sdim + s];
        const float4 ev =
            *(const float4*)(enc + (size_t)(s * Ndim + n) * Hdim + hv * 4);
        a.x += wv * ev.x; a.y += wv * ev.y; a.z += wv * ev.z; a.w += wv * ev.w;
    }
    __shared__ float4 red[128];
    if (sl == 1) red[hv] = a;
    __syncthreads();
    if (sl == 0) {
        float4 o = red[hv];
        a.x += o.x; a.y += o.y; a.z += o.z; a.w += o.w;
        float* dst = ctx + n * Hdim + hv * 4;
        atomicAdd(dst + 0, a.x);
        atomicAdd(dst + 1, a.y);
        atomicAdd(dst + 2, a.z);
        atomicAdd(dst + 3, a.w);
    }
}

extern "C" void kernel_launch(void* const* d_in, const int* in_sizes, int n_in,
                              void* d_out, int out_size, void* d_ws,
                              size_t ws_size, hipStream_t stream) {
    const float* hidden = (const float*)d_in[0];
    const float* enc    = (const float*)d_in[1];
    const float* Ww     = (const float*)d_in[2];
    const float* Wb     = (const float*)d_in[3];
    const float* Uw     = (const float*)d_in[4];
    const float* Ubias  = (const float*)d_in[5];
    const float* vw     = (const float*)d_in[6];
    const float* vbp    = (const float*)d_in[7];

    float* out = (float*)d_out;  // [0,16384): context [N,H]; then weights [S,N]

    char* ws = (char*)d_ws;
    float* bias          = (float*)(ws);                       // 64 KB
    unsigned short* Ub16 = (unsigned short*)(ws + 65536);      // 512 KB
    float* score         = (float*)(ws + 65536 + 524288);      // 512 KB
    float* wts           = (float*)(ws + 65536 + 2 * 524288);  // 512 KB

    hipMemsetAsync(d_out, 0, Ndim * Hdim * sizeof(float), stream);
    k_prep_bias<<<64, 256, 0, stream>>>(hidden, Ww, Wb, Ubias, bias);
    k_cvt<<<256, 256, 0, stream>>>(Uw, Ub16);
    k_gemm_score<<<Mdim / BM, 512, 0, stream>>>(enc, Ub16, bias, vw, vbp, score);
    k_softmax<<<Ndim, 256, 0, stream>>>(score, wts, out + Ndim * Hdim);
    k_context<<<Ndim * (Sdim / 256), 256, 0, stream>>>(enc, wts, out);
}

// Round 3
// 537.065 us; speedup vs baseline: 1.0733x; 1.0733x over previous
//
#include <hip/hip_runtime.h>
#include <hip/hip_bf16.h>

#define Sdim 4096
#define Ndim 32
#define Hdim 512
#define Mdim (Sdim * Ndim)

#define BM 128
#define BN 256
#define BK 32

typedef __bf16 bf16x8 __attribute__((ext_vector_type(8)));
typedef float f32x4 __attribute__((ext_vector_type(4)));
typedef unsigned short ushort8v __attribute__((ext_vector_type(8)));

__device__ __forceinline__ void load_lds16(const void* g, void* l) {
    __builtin_amdgcn_global_load_lds(
        (const __attribute__((address_space(1))) void*)g,
        (__attribute__((address_space(3))) void*)l, 16, 0, 0);
}

__device__ __forceinline__ float ftanh(float x) {
    float e = __expf(2.f * x);
    return 1.f - 2.f / (e + 1.f);
}

// ---------------- bias[n][c] = hidden[n]·Ww[c] + Wb[c] + Ub[c]
__global__ __launch_bounds__(256) void k_prep_bias(
    const float* __restrict__ hidden, const float* __restrict__ Ww,
    const float* __restrict__ Wb, const float* __restrict__ Ubias,
    float* __restrict__ bias) {
    const int t = threadIdx.x, w = t >> 6, lane = t & 63;
    const int cc = blockIdx.x * 4 + w;
    const float4 w0 = *(const float4*)(Ww + (size_t)cc * Hdim + lane * 8);
    const float4 w1 = *(const float4*)(Ww + (size_t)cc * Hdim + lane * 8 + 4);
    const float wb = Wb[cc] + Ubias[cc];
    for (int n = 0; n < Ndim; ++n) {
        const float4 h0 = *(const float4*)(hidden + n * Hdim + lane * 8);
        const float4 h1 = *(const float4*)(hidden + n * Hdim + lane * 8 + 4);
        float p = w0.x * h0.x + w0.y * h0.y + w0.z * h0.z + w0.w * h0.w +
                  w1.x * h1.x + w1.y * h1.y + w1.z * h1.z + w1.w * h1.w;
        p += __shfl_xor(p, 1);  p += __shfl_xor(p, 2);
        p += __shfl_xor(p, 4);  p += __shfl_xor(p, 8);
        p += __shfl_xor(p, 16); p += __shfl_xor(p, 32);
        if (lane == 0) bias[n * Hdim + cc] = p + wb;
    }
}

// ---------------- U_w fp32 -> bf16 (packed cvt)
__global__ __launch_bounds__(256) void k_cvt(
    const float* __restrict__ src, unsigned short* __restrict__ dst) {
    const int i = blockIdx.x * 256 + threadIdx.x;
    float4 v = ((const float4*)src)[i];
    union { __hip_bfloat162 h[2]; ushort4 u; } r;
    r.h[0] = __float22bfloat162_rn(make_float2(v.x, v.y));
    r.h[1] = __float22bfloat162_rn(make_float2(v.z, v.w));
    ((ushort4*)dst)[i] = r.u;
}

// ---------------- fused partial score: scorep[colblk][n][s] =
//                  sum_{col in colblk} v[col]*tanh(enc@U_wT + bias[n])[col]
// 128x256 tile, 8 waves (2M x 4N), 16x16x32 bf16 MFMA, BK=32.
__global__ __launch_bounds__(512, 4) void k_gemm_score(
    const float* __restrict__ enc,          // [M, H] fp32
    const unsigned short* __restrict__ Ub,  // [H, H] bf16, row=out col, k contig
    const float* __restrict__ bias,         // [N, H]
    const float* __restrict__ vw,           // [H]
    float* __restrict__ scorep) {           // [2][N, S] partials
    __shared__ __align__(16) unsigned short Asm[BM][40];  // 80B rows
    __shared__ __align__(16) unsigned short Bsm[BN * BK]; // linear, swizzled
    __shared__ float ssm[4][BM];

    const int t = threadIdx.x;
    const int lane = t & 63;
    const int w = t >> 6;
    const int wM = w >> 2;
    const int wN = w & 3;
    const int c = lane & 15;
    const int q = lane >> 4;

    const int rowblk = blockIdx.x >> 1;
    const int colblk = blockIdx.x & 1;
    const int mBase = rowblk * BM;
    const int colBase = colblk * BN;

    // A staging: thread -> row t>>2, 8-float chunk t&3 (contiguous 32B load)
    const int ar = t >> 2;
    const int aq = t & 3;
    const int asw = ((ar >> 3) & 1) << 1;  // half-swap swizzle
    const float* aptr = enc + (size_t)(mBase + ar) * Hdim + aq * 8;
    unsigned short* awr = &Asm[ar][(aq ^ asw) * 8];

    // B staging: 2 global_load_lds issues/thread; source chunk XOR-swizzled
    const int bsw = (lane & 3) ^ ((lane >> 4) & 3);
    const unsigned short* bptr0 =
        Ub + (size_t)(colBase + w * 16 + (lane >> 2)) * Hdim + bsw * 8;
    const unsigned short* bptr1 =
        Ub + (size_t)(colBase + 128 + w * 16 + (lane >> 2)) * Hdim + bsw * 8;
    unsigned short* bdst0 = &Bsm[(w * 16) * BK];
    unsigned short* bdst1 = &Bsm[(128 + w * 16) * BK];

    const int sA = ((c >> 3) & 1) << 1;  // A un-swizzle (lane const)
    const int sB = c >> 2;               // B un-swizzle (lane const)

    f32x4 acc[4][4];
#pragma unroll
    for (int i = 0; i < 4; ++i)
#pragma unroll
        for (int j = 0; j < 4; ++j) acc[i][j] = (f32x4){0.f, 0.f, 0.f, 0.f};

    for (int kk = 0; kk < Hdim / BK; ++kk) {
        __syncthreads();
        const float4 f0 = *(const float4*)(aptr + kk * BK);
        const float4 f1 = *(const float4*)(aptr + kk * BK + 4);
        union { __hip_bfloat162 h[4]; ushort8v v; } pk;
        pk.h[0] = __float22bfloat162_rn(make_float2(f0.x, f0.y));
        pk.h[1] = __float22bfloat162_rn(make_float2(f0.z, f0.w));
        pk.h[2] = __float22bfloat162_rn(make_float2(f1.x, f1.y));
        pk.h[3] = __float22bfloat162_rn(make_float2(f1.z, f1.w));
        *(ushort8v*)awr = pk.v;
        load_lds16(bptr0 + kk * BK, bdst0);
        load_lds16(bptr1 + kk * BK, bdst1);
        __syncthreads();

        bf16x8 af[4], bfr[4];
#pragma unroll
        for (int mi = 0; mi < 4; ++mi)
            af[mi] = *(const bf16x8*)&Asm[wM * 64 + mi * 16 + c][(q ^ sA) * 8];
#pragma unroll
        for (int ni = 0; ni < 4; ++ni) {
            const int col = wN * 64 + ni * 16 + c;
            bfr[ni] = *(const bf16x8*)&Bsm[col * BK + (q ^ sB) * 8];
        }
#pragma unroll
        for (int mi = 0; mi < 4; ++mi)
#pragma unroll
            for (int ni = 0; ni < 4; ++ni)
                acc[mi][ni] = __builtin_amdgcn_mfma_f32_16x16x32_bf16(
                    af[mi], bfr[ni], acc[mi][ni], 0, 0, 0);
    }

    // epilogue: per-row partial of v·tanh(acc + bias)  (v_b cancels in softmax)
    float vcol[4];
#pragma unroll
    for (int ni = 0; ni < 4; ++ni) vcol[ni] = vw[colBase + wN * 64 + ni * 16 + c];

#pragma unroll
    for (int mi = 0; mi < 4; ++mi) {
#pragma unroll
        for (int reg = 0; reg < 4; ++reg) {
            const int rl = wM * 64 + mi * 16 + q * 4 + reg;
            const int n = rl & 31;  // mBase % 32 == 0
            float p = 0.f;
#pragma unroll
            for (int ni = 0; ni < 4; ++ni) {
                const int col = colBase + wN * 64 + ni * 16 + c;
                float e = acc[mi][ni][reg] + bias[n * Hdim + col];
                p += vcol[ni] * ftanh(e);
            }
            p += __shfl_xor(p, 1);
            p += __shfl_xor(p, 2);
            p += __shfl_xor(p, 4);
            p += __shfl_xor(p, 8);
            if (c == 0) ssm[wN][rl] = p;
        }
    }
    __syncthreads();
    if (t < BM) {
        const int m = mBase + t;
        const float s = ssm[0][t] + ssm[1][t] + ssm[2][t] + ssm[3][t];
        scorep[colblk * Mdim + (m & 31) * Sdim + (m >> 5)] = s;
    }
}

// ---------------- softmax over S per n; score = score0 + score1
__global__ __launch_bounds__(256) void k_softmax(
    const float* __restrict__ scorep,  // [2][N][S]
    float* __restrict__ out_w) {       // d_out+16384, [S][N]
    const int n = blockIdx.x;
    const int t = threadIdx.x;
    const int w = t >> 6;
    __shared__ float row[Sdim];
    __shared__ float red[8];
    const float4* s0 = (const float4*)(scorep + n * Sdim);
    const float4* s1 = (const float4*)(scorep + Mdim + n * Sdim);

    float mx = -1e30f;
    for (int i = t; i < Sdim / 4; i += 256) {
        float4 a = s0[i], b = s1[i];
        float4 v;
        v.x = a.x + b.x; v.y = a.y + b.y; v.z = a.z + b.z; v.w = a.w + b.w;
        ((float4*)row)[i] = v;
        mx = fmaxf(mx, fmaxf(fmaxf(v.x, v.y), fmaxf(v.z, v.w)));
    }
#pragma unroll
    for (int o = 32; o > 0; o >>= 1) mx = fmaxf(mx, __shfl_xor(mx, o));
    if ((t & 63) == 0) red[w] = mx;
    __syncthreads();
    mx = fmaxf(fmaxf(red[0], red[1]), fmaxf(red[2], red[3]));

    float sum = 0.f;
    for (int i = t; i < Sdim; i += 256) sum += __expf(row[i] - mx);
#pragma unroll
    for (int o = 32; o > 0; o >>= 1) sum += __shfl_xor(sum, o);
    if ((t & 63) == 0) red[4 + w] = sum;
    __syncthreads();
    sum = red[4] + red[5] + red[6] + red[7];
    const float inv = 1.f / sum;
    for (int i = t; i < Sdim; i += 256)
        out_w[i * Ndim + n] = __expf(row[i] - mx) * inv;
}

// ---------------- context partials: part[sc][n][h] = sum_{s in chunk} w*enc
__global__ __launch_bounds__(256) void k_context(
    const float* __restrict__ enc, const float* __restrict__ wts,  // [S][N]
    float* __restrict__ part) {
    const int n = blockIdx.x & 31;
    const int sc = blockIdx.x >> 5;  // 0..15
    const int s0 = sc * 256;
    const int t = threadIdx.x;
    const int hv = t & 127;
    const int sl = t >> 7;  // 0..1
    float4 a0 = {0.f, 0.f, 0.f, 0.f}, a1 = {0.f, 0.f, 0.f, 0.f};
    for (int i = sl * 2; i < 256; i += 4) {
        const float w0 = wts[(size_t)(s0 + i) * Ndim + n];
        const float w1 = wts[(size_t)(s0 + i + 1) * Ndim + n];
        const float4 e0 =
            *(const float4*)(enc + ((size_t)(s0 + i) * Ndim + n) * Hdim + hv * 4);
        const float4 e1 =
            *(const float4*)(enc + ((size_t)(s0 + i + 1) * Ndim + n) * Hdim + hv * 4);
        a0.x += w0 * e0.x; a0.y += w0 * e0.y; a0.z += w0 * e0.z; a0.w += w0 * e0.w;
        a1.x += w1 * e1.x; a1.y += w1 * e1.y; a1.z += w1 * e1.z; a1.w += w1 * e1.w;
    }
    a0.x += a1.x; a0.y += a1.y; a0.z += a1.z; a0.w += a1.w;
    __shared__ float4 red[128];
    if (sl == 1) red[hv] = a0;
    __syncthreads();
    if (sl == 0) {
        const float4 b = red[hv];
        float4 r;
        r.x = a0.x + b.x; r.y = a0.y + b.y; r.z = a0.z + b.z; r.w = a0.w + b.w;
        *(float4*)(part + (size_t)(sc * 32 + n) * Hdim + hv * 4) = r;
    }
}

// ---------------- reduce 16 partial chunks -> context [N,H]
__global__ __launch_bounds__(256) void k_ctx_reduce(
    const float* __restrict__ part, float* __restrict__ out) {
    const int j = blockIdx.x * 256 + threadIdx.x;  // float4 index, 4096 total
    float4 s = {0.f, 0.f, 0.f, 0.f};
    for (int i = 0; i < 16; ++i) {
        const float4 v = ((const float4*)part)[i * 4096 + j];
        s.x += v.x; s.y += v.y; s.z += v.z; s.w += v.w;
    }
    ((float4*)out)[j] = s;
}

extern "C" void kernel_launch(void* const* d_in, const int* in_sizes, int n_in,
                              void* d_out, int out_size, void* d_ws,
                              size_t ws_size, hipStream_t stream) {
    const float* hidden = (const float*)d_in[0];
    const float* enc    = (const float*)d_in[1];
    const float* Ww     = (const float*)d_in[2];
    const float* Wb     = (const float*)d_in[3];
    const float* Uw     = (const float*)d_in[4];
    const float* Ubias  = (const float*)d_in[5];
    const float* vw     = (const float*)d_in[6];

    float* out = (float*)d_out;  // [0,16384): context; [16384,...): weights [S,N]

    char* ws = (char*)d_ws;
    float* bias          = (float*)(ws);                        // 64 KB
    unsigned short* Ub16 = (unsigned short*)(ws + (64 << 10));  // 512 KB
    float* scorep        = (float*)(ws + (576 << 10));          // 2x512 KB
    // part aliases [64K,1088K): Ub16 + scorep[0] dead after softmax
    float* part          = (float*)(ws + (64 << 10));           // 1 MB

    k_prep_bias<<<128, 256, 0, stream>>>(hidden, Ww, Wb, Ubias, bias);
    k_cvt<<<256, 256, 0, stream>>>(Uw, Ub16);
    k_gemm_score<<<(Mdim / BM) * 2, 512, 0, stream>>>(enc, Ub16, bias, vw,
                                                      scorep);
    k_softmax<<<Ndim, 256, 0, stream>>>(scorep, out + Ndim * Hdim);
    k_context<<<Ndim * (Sdim / 256), 256, 0, stream>>>(enc, out + Ndim * Hdim,
                                                       part);
    k_ctx_reduce<<<16, 256, 0, stream>>>(part, out);
}